// Round 15
// baseline (72.373 us; speedup 1.0000x reference)
//
#include <hip/hip_runtime.h>
#include <hip/hip_bf16.h>

// GAT fused forward loss.
// R15: single change vs R14 (65.5us champion): k_mattn SC=64 (NT=4, adj
// preload 8 loads = 32 VGPR, (256,6) -> 24 waves/CU vs 16). R14's k_mattn was
// grid-limited to 4 waves/SIMD with ~170 VGPR demand against a 128 cap.
// k_wh stays LDS-staged (W L2 traffic 67MB); k_loss/k_reduce unchanged.
// Structure: sampled rows (only h_all[idx_train] live), factored exp
// (no transcendental in inner loop), MFMA j-amortization over 16 samples,
// Z via MFMA vs ones. relu(elu(x))==relu(x); no softmax max-shift (|s+d|<~8).

#define NN 8192
#define FTDIM 512
#define CDIM 64
#define NTRAIN 1024
#define LOG2E 1.44269504088896f

typedef __attribute__((ext_vector_type(8))) short short8;
typedef __attribute__((ext_vector_type(4))) float f32x4;
typedef __attribute__((ext_vector_type(4))) int i32x4;

static __device__ __forceinline__ unsigned short f2bf(float x) {
    return __bfloat16_as_ushort(__float2bfloat16(x));
}

// ---------------------------------------------------------------------------
// Kernel A (R14): Wh = feat @ W, W LDS-staged. Block = 4 waves; wave = 4 rows;
// 512 blocks (2/CU -> 8 waves/CU). Two K-halves: stage W[half][256][64] (64KB)
// cooperatively, barrier, FMA 4 feat rows against LDS (lane c = column).
// Epilogue: Vt2[jblk][c][e] = bf16(Wh[jblk*8+e][c]) + factored-exp tables
//   sQ[i]=(2^s', 2^(0.2s'), 2^(-s'));  dE1=2^d', dE2=2^(0.2d')
// (s',d' log2e-scaled). P = (e1>th ? E1*e1 : E2*e2) == exp(lrelu(s+d)).
// ---------------------------------------------------------------------------
__global__ __launch_bounds__(256) void k_wh(
    const float* __restrict__ feat, const float* __restrict__ W,
    const float* __restrict__ av, unsigned short* __restrict__ Vt2,
    float4* __restrict__ sQ, float* __restrict__ dE1, float* __restrict__ dE2)
{
    __shared__ float wlds[256 * CDIM];   // 64 KB

    const int tid  = threadIdx.x;
    const int lane = tid & 63;
    const int wv   = tid >> 6;
    const int gw   = blockIdx.x * 4 + wv;     // 0..2047
    const int row0 = gw * 4;
    const int c    = lane;

    float acc[4] = {0.f, 0.f, 0.f, 0.f};

#pragma unroll
    for (int half = 0; half < 2; ++half) {
        if (half) __syncthreads();           // prior half's reads done
#pragma unroll
        for (int q = 0; q < 16; ++q) {
            const int idx = q * 256 + tid;
            *(f32x4*)&wlds[idx * 4] =
                *(const f32x4*)(W + half * (256 * CDIM) + idx * 4);
        }
        __syncthreads();

        const float* __restrict__ fb = feat + half * 256;
        for (int k = 0; k < 256; k += 4) {
            f32x4 f[4];
#pragma unroll
            for (int r = 0; r < 4; ++r)
                f[r] = *(const f32x4*)(fb + (size_t)(row0 + r) * FTDIM + k);
#pragma unroll
            for (int kk = 0; kk < 4; ++kk) {
                const float wval = wlds[(k + kk) * CDIM + c];
#pragma unroll
                for (int r = 0; r < 4; ++r)
                    acc[r] = fmaf(f[r][kk], wval, acc[r]);
            }
        }
    }

    ushort4 v4;
    v4.x = f2bf(acc[0]); v4.y = f2bf(acc[1]);
    v4.z = f2bf(acc[2]); v4.w = f2bf(acc[3]);
    *(ushort4*)(Vt2 + (size_t)(row0 >> 3) * 512 + c * 8 + (row0 & 7)) = v4;

    const float a1 = av[c], a2 = av[CDIM + c];
#pragma unroll
    for (int r = 0; r < 4; ++r) {
        float s_ = acc[r] * a1;
        float d_ = acc[r] * a2;
#pragma unroll
        for (int off = 32; off; off >>= 1) {
            s_ += __shfl_xor(s_, off);
            d_ += __shfl_xor(d_, off);
        }
        if (lane == 0) {
            const float sp = s_ * LOG2E, dp_ = d_ * LOG2E;
            sQ[row0 + r] = make_float4(__builtin_amdgcn_exp2f(sp),
                                       __builtin_amdgcn_exp2f(0.2f * sp),
                                       __builtin_amdgcn_exp2f(-sp), 0.f);
            dE1[row0 + r] = __builtin_amdgcn_exp2f(dp_);
            dE2[row0 + r] = __builtin_amdgcn_exp2f(0.2f * dp_);
        }
    }
}

// ---------------------------------------------------------------------------
// Kernel M (template SCL, MINW): wave = (layer l, sample-block sb, chunk sc).
// Prologue: all NT tiles' adj loads back-to-back (cold stream, paid once),
// compressed to mbits[NT]. Main loop: 2-deep pipeline over L2-hot
// dE1/dE2/Vt2; p = bit ? (e1>th ? E1*e1 : E2*e2) : 0 -> bf16 A-frag;
// 4 MFMAs numerator + 1 vs ones = Z. Partials [sample][layer][chunk][c].
// SC=64: NT=4, adj preload 32 VGPR, (256,6) -> 24 waves/CU.
// ---------------------------------------------------------------------------
struct TileS {
    f32x4 a0, a1, b0, b1;
    short8 v0, v1, v2, v3;
};

template<int SCL, int MINW>
__global__ __launch_bounds__(256, MINW) void k_mattn(
    const int* __restrict__ adj1, const int* __restrict__ adj2,
    const unsigned short* __restrict__ Vt2, const float4* __restrict__ sQ,
    const float* __restrict__ dE1, const float* __restrict__ dE2,
    const int* __restrict__ idxt,
    float* __restrict__ numPart, float* __restrict__ zPart)
{
    constexpr int NT = (NN >> SCL) >> 5;
    const int lane = threadIdx.x & 63;
    const int w = (int)((blockIdx.x * blockDim.x + threadIdx.x) >> 6);
    const int l   = w >> (6 + SCL);
    const int rem = w & ((64 << SCL) - 1);
    const int sb  = rem >> SCL;
    const int sc  = rem & ((1 << SCL) - 1);

    const int r  = lane & 15;
    const int kg = lane >> 4;

    const int i = idxt[sb * 16 + r];
    const float4 sq = sQ[i];
    const float E1 = sq.x, E2 = sq.y, th = sq.z;

    const int j0 = sc * (NN >> SCL);
    const int* __restrict__ arow = (l ? adj2 : adj1) + (size_t)i * NN + j0 + kg * 8;
    const float* __restrict__ d1p = dE1 + j0 + kg * 8;
    const float* __restrict__ d2p = dE2 + j0 + kg * 8;
    const unsigned short* __restrict__ vbase =
        Vt2 + (((size_t)j0 >> 3) << 9) + ((size_t)kg << 9) + (r << 3);

    // ---- adj preload: issue all loads back-to-back, compress to bits ----
    i32x4 am0[NT], am1[NT];
#pragma unroll
    for (int t = 0; t < NT; ++t) {
        am0[t] = *(const i32x4*)(arow + t * 32);
        am1[t] = *(const i32x4*)(arow + t * 32 + 4);
    }
    unsigned mbits[NT];
#pragma unroll
    for (int t = 0; t < NT; ++t) {
        unsigned m = 0;
#pragma unroll
        for (int e = 0; e < 4; ++e) {
            m |= (am0[t][e] != 0 ? 1u : 0u) << e;
            m |= (am1[t][e] != 0 ? 1u : 0u) << (4 + e);
        }
        mbits[t] = m;
    }

    short8 bOnes;
#pragma unroll
    for (int e = 0; e < 8; ++e) bOnes[e] = (short)0x3F80;   // bf16 1.0

    f32x4 acc0 = {0.f, 0.f, 0.f, 0.f};
    f32x4 acc1 = acc0, acc2 = acc0, acc3 = acc0, accz = acc0;

    TileS tA, tB;

#define LOADT(T, JT) do { const int _jr = (JT) * 32;                           \
    T.a0 = *(const f32x4*)(d1p + _jr);                                         \
    T.a1 = *(const f32x4*)(d1p + _jr + 4);                                     \
    T.b0 = *(const f32x4*)(d2p + _jr);                                         \
    T.b1 = *(const f32x4*)(d2p + _jr + 4);                                     \
    const unsigned short* _vp = vbase + ((size_t)(JT) << 11);                  \
    T.v0 = *(const short8*)(_vp);                                              \
    T.v1 = *(const short8*)(_vp + 128);                                        \
    T.v2 = *(const short8*)(_vp + 256);                                        \
    T.v3 = *(const short8*)(_vp + 384);                                        \
} while (0)

#define COMPT(T, JT) do {                                                      \
    const unsigned _mb = mbits[JT];                                            \
    short8 af;                                                                 \
    _Pragma("unroll")                                                          \
    for (int e = 0; e < 8; ++e) {                                              \
        const float e1 = (e < 4) ? T.a0[e & 3] : T.a1[e & 3];                  \
        const float e2 = (e < 4) ? T.b0[e & 3] : T.b1[e & 3];                  \
        const bool pos = e1 > th;                                              \
        float p = (pos ? e1 : e2) * (pos ? E1 : E2);                           \
        p = ((_mb >> e) & 1u) ? p : 0.f;                                       \
        af[e] = (short)f2bf(p);                                                \
    }                                                                          \
    acc0 = __builtin_amdgcn_mfma_f32_16x16x32_bf16(af, T.v0, acc0, 0, 0, 0);   \
    acc1 = __builtin_amdgcn_mfma_f32_16x16x32_bf16(af, T.v1, acc1, 0, 0, 0);   \
    acc2 = __builtin_amdgcn_mfma_f32_16x16x32_bf16(af, T.v2, acc2, 0, 0, 0);   \
    acc3 = __builtin_amdgcn_mfma_f32_16x16x32_bf16(af, T.v3, acc3, 0, 0, 0);   \
    accz = __builtin_amdgcn_mfma_f32_16x16x32_bf16(af, bOnes, accz, 0, 0, 0);  \
} while (0)

    LOADT(tA, 0);
#pragma unroll
    for (int jt = 0; jt < NT - 2; jt += 2) {
        LOADT(tB, jt + 1);
        COMPT(tA, jt);
        LOADT(tA, jt + 2);
        COMPT(tB, jt + 1);
    }
    LOADT(tB, NT - 1);
    COMPT(tA, NT - 2);
    COMPT(tB, NT - 1);
#undef LOADT
#undef COMPT

    // D layout: n-col = r (class), m-row = kg*4+q (sample within block).
    constexpr int SC = 1 << SCL;
#pragma unroll
    for (int q = 0; q < 4; ++q) {
        const int ks = sb * 16 + kg * 4 + q;
        const size_t slot = ((size_t)ks * 2 + l) * SC + sc;
        float* op = numPart + slot * CDIM + r;
        op[0]  = acc0[q];
        op[16] = acc1[q];
        op[32] = acc2[q];
        op[48] = acc3[q];
        if (r == 0) zPart[slot] = accz[q];
    }
}

// ---------------------------------------------------------------------------
// Kernel C: per-sample loss. One wave per sample k, lane = class. Partials for
// (k,l) contiguous; z via lane-parallel load + butterfly.
// h = 0.5*(relu(n1/z1)+relu(n2/z2)); log-softmax over 64 lanes; NLL.
// ---------------------------------------------------------------------------
__global__ __launch_bounds__(256) void k_loss(
    const float* __restrict__ numPart, const float* __restrict__ zPart,
    const int* __restrict__ labels, const int* __restrict__ idxt,
    float* __restrict__ losses, const int scLog2)
{
    const int lane = threadIdx.x & 63;
    const int k = (int)((blockIdx.x * blockDim.x + threadIdx.x) >> 6);
    const int SC = 1 << scLog2;

    float logit = 0.f;
#pragma unroll
    for (int l = 0; l < 2; ++l) {
        const size_t base = ((size_t)k * 2 + l) * SC;
        float ns = 0.f;
#pragma unroll 16
        for (int s = 0; s < SC; ++s)
            ns += numPart[(base + s) * CDIM + lane];
        float zs = (lane < SC) ? zPart[base + lane] : 0.f;
        if (SC > 64) {
            for (int s = 64 + lane; s < SC; s += 64) zs += zPart[base + s];
        }
#pragma unroll
        for (int off = 32; off; off >>= 1) zs += __shfl_xor(zs, off);
        logit += fmaxf(ns / zs, 0.f);   // relu(elu(x)) == relu(x)
    }
    logit *= 0.5f;

    float m = logit;
#pragma unroll
    for (int off = 32; off; off >>= 1) m = fmaxf(m, __shfl_xor(m, off));
    float ex = __expf(logit - m);
    float sum = ex;
#pragma unroll
    for (int off = 32; off; off >>= 1) sum += __shfl_xor(sum, off);
    const float logp = logit - m - __logf(sum);

    const int y = labels[idxt[k]];
    const float t = __shfl(logp, y);
    if (lane == 0) losses[k] = -t;
}

// ---------------------------------------------------------------------------
// Kernel D: mean of 1024 per-sample losses -> d_out[0].
// ---------------------------------------------------------------------------
__global__ __launch_bounds__(256) void k_reduce(
    const float* __restrict__ losses, float* __restrict__ out)
{
    __shared__ float sbuf[4];
    const int tid = threadIdx.x;
    float v = losses[tid] + losses[tid + 256] + losses[tid + 512] + losses[tid + 768];
#pragma unroll
    for (int off = 32; off; off >>= 1) v += __shfl_xor(v, off);
    if ((tid & 63) == 0) sbuf[tid >> 6] = v;
    __syncthreads();
    if (tid == 0) out[0] = (sbuf[0] + sbuf[1] + sbuf[2] + sbuf[3]) * (1.f / 1024.f);
}

// ---------------------------------------------------------------------------
extern "C" void kernel_launch(void* const* d_in, const int* in_sizes, int n_in,
                              void* d_out, int out_size, void* d_ws, size_t ws_size,
                              hipStream_t stream)
{
    const float* feat   = (const float*)d_in[0];
    const float* W      = (const float*)d_in[1];
    const float* av     = (const float*)d_in[2];
    const int*   adj1   = (const int*)d_in[3];
    const int*   adj2   = (const int*)d_in[4];
    const int*   labels = (const int*)d_in[5];
    const int*   idxt   = (const int*)d_in[6];

    const size_t HEAD = (1u << 20) + (192u << 10);  // Vt2 1MB + sQ 128KB + dE1/2 64KB

    auto needed = [&](int scl) -> size_t {
        const size_t SC = (size_t)1 << scl;
        return HEAD + 2 * SC * NTRAIN * CDIM * sizeof(float)
                    + 2 * SC * NTRAIN * sizeof(float)
                    + NTRAIN * sizeof(float);
    };
    const int scLog2 = (ws_size >= needed(6)) ? 6
                     : (ws_size >= needed(5)) ? 5 : 4;
    const int SC = 1 << scLog2;

    char* ws = (char*)d_ws;
    unsigned short* Vt2 = (unsigned short*)ws;                  // 1 MB
    float4* sQ  = (float4*)(ws + (1u << 20));                   // 128 KB
    float*  dE1 = (float*)(ws + (1u << 20) + (128u << 10));     // 32 KB
    float*  dE2 = (float*)(ws + (1u << 20) + (160u << 10));     // 32 KB
    float*  numPart = (float*)(ws + HEAD);
    float*  zPart   = numPart + 2ull * SC * NTRAIN * CDIM;
    float*  losses  = zPart + 2ull * SC * NTRAIN;

    hipLaunchKernelGGL(k_wh, dim3(512), dim3(256), 0, stream,
                       feat, W, av, Vt2, sQ, dE1, dE2);
    if (scLog2 == 6)
        hipLaunchKernelGGL((k_mattn<6, 6>), dim3(32 * 64), dim3(256), 0, stream,
                           adj1, adj2, Vt2, sQ, dE1, dE2, idxt, numPart, zPart);
    else if (scLog2 == 5)
        hipLaunchKernelGGL((k_mattn<5, 4>), dim3(32 * 32), dim3(256), 0, stream,
                           adj1, adj2, Vt2, sQ, dE1, dE2, idxt, numPart, zPart);
    else
        hipLaunchKernelGGL((k_mattn<4, 4>), dim3(32 * 16), dim3(256), 0, stream,
                           adj1, adj2, Vt2, sQ, dE1, dE2, idxt, numPart, zPart);
    hipLaunchKernelGGL(k_loss, dim3(NTRAIN / 4), dim3(256), 0, stream,
                       numPart, zPart, labels, idxt, losses, scLog2);
    hipLaunchKernelGGL(k_reduce, dim3(1), dim3(256), 0, stream,
                       losses, (float*)d_out);
}

// Round 16
// 65.773 us; speedup vs baseline: 1.1003x; 1.1003x over previous
//
#include <hip/hip_runtime.h>
#include <hip/hip_bf16.h>

// GAT fused forward loss.
// R16: single change vs R14 (65.5us champion): k_mattn adj preload split into
// 2 groups of 4 tiles (peak adj regs 64->32; total VGPR demand ~105 < 128 cap
// at (256,4)) to eliminate suspected spill/serialization. R15 proved SC=64
// regresses (+6.9us partial traffic); SC=32 kept.
// Structure: sampled rows (only h_all[idx_train] live), factored exp
// (no transcendental in inner loop), MFMA j-amortization over 16 samples,
// Z via MFMA vs ones. relu(elu(x))==relu(x); no softmax max-shift (|s+d|<~8).

#define NN 8192
#define FTDIM 512
#define CDIM 64
#define NTRAIN 1024
#define LOG2E 1.44269504088896f

typedef __attribute__((ext_vector_type(8))) short short8;
typedef __attribute__((ext_vector_type(4))) float f32x4;
typedef __attribute__((ext_vector_type(4))) int i32x4;

static __device__ __forceinline__ unsigned short f2bf(float x) {
    return __bfloat16_as_ushort(__float2bfloat16(x));
}

// ---------------------------------------------------------------------------
// Kernel A (R14): Wh = feat @ W, W LDS-staged. Block = 4 waves; wave = 4 rows;
// 512 blocks (2/CU -> 8 waves/CU). Two K-halves: stage W[half][256][64] (64KB)
// cooperatively, barrier, FMA 4 feat rows against LDS (lane c = column).
// Epilogue: Vt2[jblk][c][e] = bf16(Wh[jblk*8+e][c]) + factored-exp tables
//   sQ[i]=(2^s', 2^(0.2s'), 2^(-s'));  dE1=2^d', dE2=2^(0.2d')
// (s',d' log2e-scaled). P = (e1>th ? E1*e1 : E2*e2) == exp(lrelu(s+d)).
// ---------------------------------------------------------------------------
__global__ __launch_bounds__(256) void k_wh(
    const float* __restrict__ feat, const float* __restrict__ W,
    const float* __restrict__ av, unsigned short* __restrict__ Vt2,
    float4* __restrict__ sQ, float* __restrict__ dE1, float* __restrict__ dE2)
{
    __shared__ float wlds[256 * CDIM];   // 64 KB

    const int tid  = threadIdx.x;
    const int lane = tid & 63;
    const int wv   = tid >> 6;
    const int gw   = blockIdx.x * 4 + wv;     // 0..2047
    const int row0 = gw * 4;
    const int c    = lane;

    float acc[4] = {0.f, 0.f, 0.f, 0.f};

#pragma unroll
    for (int half = 0; half < 2; ++half) {
        if (half) __syncthreads();           // prior half's reads done
#pragma unroll
        for (int q = 0; q < 16; ++q) {
            const int idx = q * 256 + tid;
            *(f32x4*)&wlds[idx * 4] =
                *(const f32x4*)(W + half * (256 * CDIM) + idx * 4);
        }
        __syncthreads();

        const float* __restrict__ fb = feat + half * 256;
        for (int k = 0; k < 256; k += 4) {
            f32x4 f[4];
#pragma unroll
            for (int r = 0; r < 4; ++r)
                f[r] = *(const f32x4*)(fb + (size_t)(row0 + r) * FTDIM + k);
#pragma unroll
            for (int kk = 0; kk < 4; ++kk) {
                const float wval = wlds[(k + kk) * CDIM + c];
#pragma unroll
                for (int r = 0; r < 4; ++r)
                    acc[r] = fmaf(f[r][kk], wval, acc[r]);
            }
        }
    }

    ushort4 v4;
    v4.x = f2bf(acc[0]); v4.y = f2bf(acc[1]);
    v4.z = f2bf(acc[2]); v4.w = f2bf(acc[3]);
    *(ushort4*)(Vt2 + (size_t)(row0 >> 3) * 512 + c * 8 + (row0 & 7)) = v4;

    const float a1 = av[c], a2 = av[CDIM + c];
#pragma unroll
    for (int r = 0; r < 4; ++r) {
        float s_ = acc[r] * a1;
        float d_ = acc[r] * a2;
#pragma unroll
        for (int off = 32; off; off >>= 1) {
            s_ += __shfl_xor(s_, off);
            d_ += __shfl_xor(d_, off);
        }
        if (lane == 0) {
            const float sp = s_ * LOG2E, dp_ = d_ * LOG2E;
            sQ[row0 + r] = make_float4(__builtin_amdgcn_exp2f(sp),
                                       __builtin_amdgcn_exp2f(0.2f * sp),
                                       __builtin_amdgcn_exp2f(-sp), 0.f);
            dE1[row0 + r] = __builtin_amdgcn_exp2f(dp_);
            dE2[row0 + r] = __builtin_amdgcn_exp2f(0.2f * dp_);
        }
    }
}

// ---------------------------------------------------------------------------
// Kernel M (R14 config + grouped preload): wave = (layer l, sample-block sb,
// chunk sc). Prologue: adj loads in 2 groups of 4 tiles (8 i32x4 live max),
// each group compressed to mbits before the next issues -> peak VGPR ~105,
// no spill at (256,4). Main loop: 2-deep pipeline over L2-hot dE1/dE2/Vt2;
// p = bit ? (e1>th ? E1*e1 : E2*e2) : 0 -> bf16 A-frag; 4 MFMAs numerator +
// 1 vs ones = Z. Partials [sample][layer][chunk][c].
// ---------------------------------------------------------------------------
struct TileS {
    f32x4 a0, a1, b0, b1;
    short8 v0, v1, v2, v3;
};

template<int SCL>
__global__ __launch_bounds__(256, 4) void k_mattn(
    const int* __restrict__ adj1, const int* __restrict__ adj2,
    const unsigned short* __restrict__ Vt2, const float4* __restrict__ sQ,
    const float* __restrict__ dE1, const float* __restrict__ dE2,
    const int* __restrict__ idxt,
    float* __restrict__ numPart, float* __restrict__ zPart)
{
    constexpr int NT = (NN >> SCL) >> 5;
    const int lane = threadIdx.x & 63;
    const int w = (int)((blockIdx.x * blockDim.x + threadIdx.x) >> 6);
    const int l   = w >> (6 + SCL);
    const int rem = w & ((64 << SCL) - 1);
    const int sb  = rem >> SCL;
    const int sc  = rem & ((1 << SCL) - 1);

    const int r  = lane & 15;
    const int kg = lane >> 4;

    const int i = idxt[sb * 16 + r];
    const float4 sq = sQ[i];
    const float E1 = sq.x, E2 = sq.y, th = sq.z;

    const int j0 = sc * (NN >> SCL);
    const int* __restrict__ arow = (l ? adj2 : adj1) + (size_t)i * NN + j0 + kg * 8;
    const float* __restrict__ d1p = dE1 + j0 + kg * 8;
    const float* __restrict__ d2p = dE2 + j0 + kg * 8;
    const unsigned short* __restrict__ vbase =
        Vt2 + (((size_t)j0 >> 3) << 9) + ((size_t)kg << 9) + (r << 3);

    // ---- adj preload in groups of 4 tiles (caps live adj regs at 32) ----
    unsigned mbits[NT];
#pragma unroll
    for (int g = 0; g < NT; g += 4) {
        i32x4 gm0[4], gm1[4];
#pragma unroll
        for (int t = 0; t < 4; ++t) {
            gm0[t] = *(const i32x4*)(arow + (g + t) * 32);
            gm1[t] = *(const i32x4*)(arow + (g + t) * 32 + 4);
        }
#pragma unroll
        for (int t = 0; t < 4; ++t) {
            unsigned m = 0;
#pragma unroll
            for (int e = 0; e < 4; ++e) {
                m |= (gm0[t][e] != 0 ? 1u : 0u) << e;
                m |= (gm1[t][e] != 0 ? 1u : 0u) << (4 + e);
            }
            mbits[g + t] = m;
        }
    }

    short8 bOnes;
#pragma unroll
    for (int e = 0; e < 8; ++e) bOnes[e] = (short)0x3F80;   // bf16 1.0

    f32x4 acc0 = {0.f, 0.f, 0.f, 0.f};
    f32x4 acc1 = acc0, acc2 = acc0, acc3 = acc0, accz = acc0;

    TileS tA, tB;

#define LOADT(T, JT) do { const int _jr = (JT) * 32;                           \
    T.a0 = *(const f32x4*)(d1p + _jr);                                         \
    T.a1 = *(const f32x4*)(d1p + _jr + 4);                                     \
    T.b0 = *(const f32x4*)(d2p + _jr);                                         \
    T.b1 = *(const f32x4*)(d2p + _jr + 4);                                     \
    const unsigned short* _vp = vbase + ((size_t)(JT) << 11);                  \
    T.v0 = *(const short8*)(_vp);                                              \
    T.v1 = *(const short8*)(_vp + 128);                                        \
    T.v2 = *(const short8*)(_vp + 256);                                        \
    T.v3 = *(const short8*)(_vp + 384);                                        \
} while (0)

#define COMPT(T, JT) do {                                                      \
    const unsigned _mb = mbits[JT];                                            \
    short8 af;                                                                 \
    _Pragma("unroll")                                                          \
    for (int e = 0; e < 8; ++e) {                                              \
        const float e1 = (e < 4) ? T.a0[e & 3] : T.a1[e & 3];                  \
        const float e2 = (e < 4) ? T.b0[e & 3] : T.b1[e & 3];                  \
        const bool pos = e1 > th;                                              \
        float p = (pos ? e1 : e2) * (pos ? E1 : E2);                           \
        p = ((_mb >> e) & 1u) ? p : 0.f;                                       \
        af[e] = (short)f2bf(p);                                                \
    }                                                                          \
    acc0 = __builtin_amdgcn_mfma_f32_16x16x32_bf16(af, T.v0, acc0, 0, 0, 0);   \
    acc1 = __builtin_amdgcn_mfma_f32_16x16x32_bf16(af, T.v1, acc1, 0, 0, 0);   \
    acc2 = __builtin_amdgcn_mfma_f32_16x16x32_bf16(af, T.v2, acc2, 0, 0, 0);   \
    acc3 = __builtin_amdgcn_mfma_f32_16x16x32_bf16(af, T.v3, acc3, 0, 0, 0);   \
    accz = __builtin_amdgcn_mfma_f32_16x16x32_bf16(af, bOnes, accz, 0, 0, 0);  \
} while (0)

    LOADT(tA, 0);
#pragma unroll
    for (int jt = 0; jt < NT - 2; jt += 2) {
        LOADT(tB, jt + 1);
        COMPT(tA, jt);
        LOADT(tA, jt + 2);
        COMPT(tB, jt + 1);
    }
    LOADT(tB, NT - 1);
    COMPT(tA, NT - 2);
    COMPT(tB, NT - 1);
#undef LOADT
#undef COMPT

    // D layout: n-col = r (class), m-row = kg*4+q (sample within block).
    constexpr int SC = 1 << SCL;
#pragma unroll
    for (int q = 0; q < 4; ++q) {
        const int ks = sb * 16 + kg * 4 + q;
        const size_t slot = ((size_t)ks * 2 + l) * SC + sc;
        float* op = numPart + slot * CDIM + r;
        op[0]  = acc0[q];
        op[16] = acc1[q];
        op[32] = acc2[q];
        op[48] = acc3[q];
        if (r == 0) zPart[slot] = accz[q];
    }
}

// ---------------------------------------------------------------------------
// Kernel C: per-sample loss. One wave per sample k, lane = class. Partials for
// (k,l) contiguous; z via lane-parallel load + butterfly.
// h = 0.5*(relu(n1/z1)+relu(n2/z2)); log-softmax over 64 lanes; NLL.
// ---------------------------------------------------------------------------
__global__ __launch_bounds__(256) void k_loss(
    const float* __restrict__ numPart, const float* __restrict__ zPart,
    const int* __restrict__ labels, const int* __restrict__ idxt,
    float* __restrict__ losses, const int scLog2)
{
    const int lane = threadIdx.x & 63;
    const int k = (int)((blockIdx.x * blockDim.x + threadIdx.x) >> 6);
    const int SC = 1 << scLog2;

    float logit = 0.f;
#pragma unroll
    for (int l = 0; l < 2; ++l) {
        const size_t base = ((size_t)k * 2 + l) * SC;
        float ns = 0.f;
#pragma unroll 16
        for (int s = 0; s < SC; ++s)
            ns += numPart[(base + s) * CDIM + lane];
        float zs = (lane < SC) ? zPart[base + lane] : 0.f;
#pragma unroll
        for (int off = 32; off; off >>= 1) zs += __shfl_xor(zs, off);
        logit += fmaxf(ns / zs, 0.f);   // relu(elu(x)) == relu(x)
    }
    logit *= 0.5f;

    float m = logit;
#pragma unroll
    for (int off = 32; off; off >>= 1) m = fmaxf(m, __shfl_xor(m, off));
    float ex = __expf(logit - m);
    float sum = ex;
#pragma unroll
    for (int off = 32; off; off >>= 1) sum += __shfl_xor(sum, off);
    const float logp = logit - m - __logf(sum);

    const int y = labels[idxt[k]];
    const float t = __shfl(logp, y);
    if (lane == 0) losses[k] = -t;
}

// ---------------------------------------------------------------------------
// Kernel D: mean of 1024 per-sample losses -> d_out[0].
// ---------------------------------------------------------------------------
__global__ __launch_bounds__(256) void k_reduce(
    const float* __restrict__ losses, float* __restrict__ out)
{
    __shared__ float sbuf[4];
    const int tid = threadIdx.x;
    float v = losses[tid] + losses[tid + 256] + losses[tid + 512] + losses[tid + 768];
#pragma unroll
    for (int off = 32; off; off >>= 1) v += __shfl_xor(v, off);
    if ((tid & 63) == 0) sbuf[tid >> 6] = v;
    __syncthreads();
    if (tid == 0) out[0] = (sbuf[0] + sbuf[1] + sbuf[2] + sbuf[3]) * (1.f / 1024.f);
}

// ---------------------------------------------------------------------------
extern "C" void kernel_launch(void* const* d_in, const int* in_sizes, int n_in,
                              void* d_out, int out_size, void* d_ws, size_t ws_size,
                              hipStream_t stream)
{
    const float* feat   = (const float*)d_in[0];
    const float* W      = (const float*)d_in[1];
    const float* av     = (const float*)d_in[2];
    const int*   adj1   = (const int*)d_in[3];
    const int*   adj2   = (const int*)d_in[4];
    const int*   labels = (const int*)d_in[5];
    const int*   idxt   = (const int*)d_in[6];

    const size_t HEAD = (1u << 20) + (192u << 10);  // Vt2 1MB + sQ 128KB + dE1/2 64KB

    auto needed = [&](int scl) -> size_t {
        const size_t SC = (size_t)1 << scl;
        return HEAD + 2 * SC * NTRAIN * CDIM * sizeof(float)
                    + 2 * SC * NTRAIN * sizeof(float)
                    + NTRAIN * sizeof(float);
    };
    const int scLog2 = (ws_size >= needed(5)) ? 5 : 4;
    const int SC = 1 << scLog2;

    char* ws = (char*)d_ws;
    unsigned short* Vt2 = (unsigned short*)ws;                  // 1 MB
    float4* sQ  = (float4*)(ws + (1u << 20));                   // 128 KB
    float*  dE1 = (float*)(ws + (1u << 20) + (128u << 10));     // 32 KB
    float*  dE2 = (float*)(ws + (1u << 20) + (160u << 10));     // 32 KB
    float*  numPart = (float*)(ws + HEAD);
    float*  zPart   = numPart + 2ull * SC * NTRAIN * CDIM;
    float*  losses  = zPart + 2ull * SC * NTRAIN;

    hipLaunchKernelGGL(k_wh, dim3(512), dim3(256), 0, stream,
                       feat, W, av, Vt2, sQ, dE1, dE2);
    if (scLog2 == 5)
        hipLaunchKernelGGL((k_mattn<5>), dim3(32 * 32), dim3(256), 0, stream,
                           adj1, adj2, Vt2, sQ, dE1, dE2, idxt, numPart, zPart);
    else
        hipLaunchKernelGGL((k_mattn<4>), dim3(32 * 16), dim3(256), 0, stream,
                           adj1, adj2, Vt2, sQ, dE1, dE2, idxt, numPart, zPart);
    hipLaunchKernelGGL(k_loss, dim3(NTRAIN / 4), dim3(256), 0, stream,
                       numPart, zPart, labels, idxt, losses, scLog2);
    hipLaunchKernelGGL(k_reduce, dim3(1), dim3(256), 0, stream,
                       losses, (float*)d_out);
}

// Round 17
// 64.605 us; speedup vs baseline: 1.1202x; 1.0181x over previous
//
#include <hip/hip_runtime.h>
#include <hip/hip_bf16.h>

// GAT fused forward loss.
// R17 vs R16 (65.5us plateau): two changes.
// 1) k_mattn wave->work mapping swapped: block's 4 waves = 4 sample-blocks x
//    SAME j-chunk (sc=rem>>6, sb=rem&63). They walk the same 32KB Vt2 + 2KB
//    dE window on one CU -> L1 serves ~3/4 waves (was: 4 disjoint windows,
//    all L2 round-trips). 2) numPart stored bf16 (P already bf16 in MFMA) ->
//    partial traffic halved.
// Structure: sampled rows (only h_all[idx_train] live), factored exp,
// MFMA j-amortization over 16 samples, Z via MFMA vs ones, grouped adj
// preload. relu(elu(x))==relu(x); no softmax max-shift (|s+d|<~8).

#define NN 8192
#define FTDIM 512
#define CDIM 64
#define NTRAIN 1024
#define LOG2E 1.44269504088896f

typedef __attribute__((ext_vector_type(8))) short short8;
typedef __attribute__((ext_vector_type(4))) float f32x4;
typedef __attribute__((ext_vector_type(4))) int i32x4;

static __device__ __forceinline__ unsigned short f2bf(float x) {
    return __bfloat16_as_ushort(__float2bfloat16(x));
}
static __device__ __forceinline__ float bf2f(unsigned short u) {
    return __uint_as_float((unsigned)u << 16);
}

// ---------------------------------------------------------------------------
// Kernel A (R14): Wh = feat @ W, W LDS-staged. Block = 4 waves; wave = 4 rows;
// 512 blocks (2/CU -> 8 waves/CU). Two K-halves: stage W[half][256][64] (64KB)
// cooperatively, barrier, FMA 4 feat rows against LDS (lane c = column).
// Epilogue: Vt2[jblk][c][e] = bf16(Wh[jblk*8+e][c]) + factored-exp tables
//   sQ[i]=(2^s', 2^(0.2s'), 2^(-s'));  dE1=2^d', dE2=2^(0.2d')
// (s',d' log2e-scaled). P = (e1>th ? E1*e1 : E2*e2) == exp(lrelu(s+d)).
// ---------------------------------------------------------------------------
__global__ __launch_bounds__(256) void k_wh(
    const float* __restrict__ feat, const float* __restrict__ W,
    const float* __restrict__ av, unsigned short* __restrict__ Vt2,
    float4* __restrict__ sQ, float* __restrict__ dE1, float* __restrict__ dE2)
{
    __shared__ float wlds[256 * CDIM];   // 64 KB

    const int tid  = threadIdx.x;
    const int lane = tid & 63;
    const int wv   = tid >> 6;
    const int gw   = blockIdx.x * 4 + wv;     // 0..2047
    const int row0 = gw * 4;
    const int c    = lane;

    float acc[4] = {0.f, 0.f, 0.f, 0.f};

#pragma unroll
    for (int half = 0; half < 2; ++half) {
        if (half) __syncthreads();           // prior half's reads done
#pragma unroll
        for (int q = 0; q < 16; ++q) {
            const int idx = q * 256 + tid;
            *(f32x4*)&wlds[idx * 4] =
                *(const f32x4*)(W + half * (256 * CDIM) + idx * 4);
        }
        __syncthreads();

        const float* __restrict__ fb = feat + half * 256;
        for (int k = 0; k < 256; k += 4) {
            f32x4 f[4];
#pragma unroll
            for (int r = 0; r < 4; ++r)
                f[r] = *(const f32x4*)(fb + (size_t)(row0 + r) * FTDIM + k);
#pragma unroll
            for (int kk = 0; kk < 4; ++kk) {
                const float wval = wlds[(k + kk) * CDIM + c];
#pragma unroll
                for (int r = 0; r < 4; ++r)
                    acc[r] = fmaf(f[r][kk], wval, acc[r]);
            }
        }
    }

    ushort4 v4;
    v4.x = f2bf(acc[0]); v4.y = f2bf(acc[1]);
    v4.z = f2bf(acc[2]); v4.w = f2bf(acc[3]);
    *(ushort4*)(Vt2 + (size_t)(row0 >> 3) * 512 + c * 8 + (row0 & 7)) = v4;

    const float a1 = av[c], a2 = av[CDIM + c];
#pragma unroll
    for (int r = 0; r < 4; ++r) {
        float s_ = acc[r] * a1;
        float d_ = acc[r] * a2;
#pragma unroll
        for (int off = 32; off; off >>= 1) {
            s_ += __shfl_xor(s_, off);
            d_ += __shfl_xor(d_, off);
        }
        if (lane == 0) {
            const float sp = s_ * LOG2E, dp_ = d_ * LOG2E;
            sQ[row0 + r] = make_float4(__builtin_amdgcn_exp2f(sp),
                                       __builtin_amdgcn_exp2f(0.2f * sp),
                                       __builtin_amdgcn_exp2f(-sp), 0.f);
            dE1[row0 + r] = __builtin_amdgcn_exp2f(dp_);
            dE2[row0 + r] = __builtin_amdgcn_exp2f(0.2f * dp_);
        }
    }
}

// ---------------------------------------------------------------------------
// Kernel M: wave = (layer l, sample-block sb, chunk sc) with sc-MAJOR block
// mapping: block's 4 waves = consecutive sb, same sc -> shared Vt2/dE window
// (L1-served). Prologue: adj loads in 2 groups of 4 tiles, compressed to
// mbits. Main loop: 2-deep pipeline over L2/L1-hot dE1/dE2/Vt2; p = bit ?
// (e1>th ? E1*e1 : E2*e2) : 0 -> bf16 A-frag; 4 MFMAs numerator + 1 vs ones
// = Z. Partials: numPart bf16 [sample][layer][chunk][c], zPart f32.
// ---------------------------------------------------------------------------
struct TileS {
    f32x4 a0, a1, b0, b1;
    short8 v0, v1, v2, v3;
};

template<int SCL>
__global__ __launch_bounds__(256, 4) void k_mattn(
    const int* __restrict__ adj1, const int* __restrict__ adj2,
    const unsigned short* __restrict__ Vt2, const float4* __restrict__ sQ,
    const float* __restrict__ dE1, const float* __restrict__ dE2,
    const int* __restrict__ idxt,
    unsigned short* __restrict__ numPartB, float* __restrict__ zPart)
{
    constexpr int NT = (NN >> SCL) >> 5;
    const int lane = threadIdx.x & 63;
    const int w = (int)((blockIdx.x * blockDim.x + threadIdx.x) >> 6);
    const int l   = w >> (6 + SCL);
    const int rem = w & ((64 << SCL) - 1);
    const int sc  = rem >> 6;          // sc-major: block's 4 waves share sc
    const int sb  = rem & 63;

    const int r  = lane & 15;
    const int kg = lane >> 4;

    const int i = idxt[sb * 16 + r];
    const float4 sq = sQ[i];
    const float E1 = sq.x, E2 = sq.y, th = sq.z;

    const int j0 = sc * (NN >> SCL);
    const int* __restrict__ arow = (l ? adj2 : adj1) + (size_t)i * NN + j0 + kg * 8;
    const float* __restrict__ d1p = dE1 + j0 + kg * 8;
    const float* __restrict__ d2p = dE2 + j0 + kg * 8;
    const unsigned short* __restrict__ vbase =
        Vt2 + (((size_t)j0 >> 3) << 9) + ((size_t)kg << 9) + (r << 3);

    // ---- adj preload in groups of 4 tiles (caps live adj regs at 32) ----
    unsigned mbits[NT];
#pragma unroll
    for (int g = 0; g < NT; g += 4) {
        i32x4 gm0[4], gm1[4];
#pragma unroll
        for (int t = 0; t < 4; ++t) {
            gm0[t] = *(const i32x4*)(arow + (g + t) * 32);
            gm1[t] = *(const i32x4*)(arow + (g + t) * 32 + 4);
        }
#pragma unroll
        for (int t = 0; t < 4; ++t) {
            unsigned m = 0;
#pragma unroll
            for (int e = 0; e < 4; ++e) {
                m |= (gm0[t][e] != 0 ? 1u : 0u) << e;
                m |= (gm1[t][e] != 0 ? 1u : 0u) << (4 + e);
            }
            mbits[g + t] = m;
        }
    }

    short8 bOnes;
#pragma unroll
    for (int e = 0; e < 8; ++e) bOnes[e] = (short)0x3F80;   // bf16 1.0

    f32x4 acc0 = {0.f, 0.f, 0.f, 0.f};
    f32x4 acc1 = acc0, acc2 = acc0, acc3 = acc0, accz = acc0;

    TileS tA, tB;

#define LOADT(T, JT) do { const int _jr = (JT) * 32;                           \
    T.a0 = *(const f32x4*)(d1p + _jr);                                         \
    T.a1 = *(const f32x4*)(d1p + _jr + 4);                                     \
    T.b0 = *(const f32x4*)(d2p + _jr);                                         \
    T.b1 = *(const f32x4*)(d2p + _jr + 4);                                     \
    const unsigned short* _vp = vbase + ((size_t)(JT) << 11);                  \
    T.v0 = *(const short8*)(_vp);                                              \
    T.v1 = *(const short8*)(_vp + 128);                                        \
    T.v2 = *(const short8*)(_vp + 256);                                        \
    T.v3 = *(const short8*)(_vp + 384);                                        \
} while (0)

#define COMPT(T, JT) do {                                                      \
    const unsigned _mb = mbits[JT];                                            \
    short8 af;                                                                 \
    _Pragma("unroll")                                                          \
    for (int e = 0; e < 8; ++e) {                                              \
        const float e1 = (e < 4) ? T.a0[e & 3] : T.a1[e & 3];                  \
        const float e2 = (e < 4) ? T.b0[e & 3] : T.b1[e & 3];                  \
        const bool pos = e1 > th;                                              \
        float p = (pos ? e1 : e2) * (pos ? E1 : E2);                           \
        p = ((_mb >> e) & 1u) ? p : 0.f;                                       \
        af[e] = (short)f2bf(p);                                                \
    }                                                                          \
    acc0 = __builtin_amdgcn_mfma_f32_16x16x32_bf16(af, T.v0, acc0, 0, 0, 0);   \
    acc1 = __builtin_amdgcn_mfma_f32_16x16x32_bf16(af, T.v1, acc1, 0, 0, 0);   \
    acc2 = __builtin_amdgcn_mfma_f32_16x16x32_bf16(af, T.v2, acc2, 0, 0, 0);   \
    acc3 = __builtin_amdgcn_mfma_f32_16x16x32_bf16(af, T.v3, acc3, 0, 0, 0);   \
    accz = __builtin_amdgcn_mfma_f32_16x16x32_bf16(af, bOnes, accz, 0, 0, 0);  \
} while (0)

    LOADT(tA, 0);
#pragma unroll
    for (int jt = 0; jt < NT - 2; jt += 2) {
        LOADT(tB, jt + 1);
        COMPT(tA, jt);
        LOADT(tA, jt + 2);
        COMPT(tB, jt + 1);
    }
    LOADT(tB, NT - 1);
    COMPT(tA, NT - 2);
    COMPT(tB, NT - 1);
#undef LOADT
#undef COMPT

    // D layout: n-col = r (class), m-row = kg*4+q (sample within block).
    constexpr int SC = 1 << SCL;
#pragma unroll
    for (int q = 0; q < 4; ++q) {
        const int ks = sb * 16 + kg * 4 + q;
        const size_t slot = ((size_t)ks * 2 + l) * SC + sc;
        unsigned short* op = numPartB + slot * CDIM + r;
        op[0]  = f2bf(acc0[q]);
        op[16] = f2bf(acc1[q]);
        op[32] = f2bf(acc2[q]);
        op[48] = f2bf(acc3[q]);
        if (r == 0) zPart[slot] = accz[q];
    }
}

// ---------------------------------------------------------------------------
// Kernel C: per-sample loss. One wave per sample k, lane = class. bf16
// partials for (k,l) contiguous; z via lane-parallel load + butterfly.
// h = 0.5*(relu(n1/z1)+relu(n2/z2)); log-softmax over 64 lanes; NLL.
// ---------------------------------------------------------------------------
__global__ __launch_bounds__(256) void k_loss(
    const unsigned short* __restrict__ numPartB, const float* __restrict__ zPart,
    const int* __restrict__ labels, const int* __restrict__ idxt,
    float* __restrict__ losses, const int scLog2)
{
    const int lane = threadIdx.x & 63;
    const int k = (int)((blockIdx.x * blockDim.x + threadIdx.x) >> 6);
    const int SC = 1 << scLog2;

    float logit = 0.f;
#pragma unroll
    for (int l = 0; l < 2; ++l) {
        const size_t base = ((size_t)k * 2 + l) * SC;
        float ns = 0.f;
#pragma unroll 16
        for (int s = 0; s < SC; ++s)
            ns += bf2f(numPartB[(base + s) * CDIM + lane]);
        float zs = (lane < SC) ? zPart[base + lane] : 0.f;
#pragma unroll
        for (int off = 32; off; off >>= 1) zs += __shfl_xor(zs, off);
        logit += fmaxf(ns / zs, 0.f);   // relu(elu(x)) == relu(x)
    }
    logit *= 0.5f;

    float m = logit;
#pragma unroll
    for (int off = 32; off; off >>= 1) m = fmaxf(m, __shfl_xor(m, off));
    float ex = __expf(logit - m);
    float sum = ex;
#pragma unroll
    for (int off = 32; off; off >>= 1) sum += __shfl_xor(sum, off);
    const float logp = logit - m - __logf(sum);

    const int y = labels[idxt[k]];
    const float t = __shfl(logp, y);
    if (lane == 0) losses[k] = -t;
}

// ---------------------------------------------------------------------------
// Kernel D: mean of 1024 per-sample losses -> d_out[0].
// ---------------------------------------------------------------------------
__global__ __launch_bounds__(256) void k_reduce(
    const float* __restrict__ losses, float* __restrict__ out)
{
    __shared__ float sbuf[4];
    const int tid = threadIdx.x;
    float v = losses[tid] + losses[tid + 256] + losses[tid + 512] + losses[tid + 768];
#pragma unroll
    for (int off = 32; off; off >>= 1) v += __shfl_xor(v, off);
    if ((tid & 63) == 0) sbuf[tid >> 6] = v;
    __syncthreads();
    if (tid == 0) out[0] = (sbuf[0] + sbuf[1] + sbuf[2] + sbuf[3]) * (1.f / 1024.f);
}

// ---------------------------------------------------------------------------
extern "C" void kernel_launch(void* const* d_in, const int* in_sizes, int n_in,
                              void* d_out, int out_size, void* d_ws, size_t ws_size,
                              hipStream_t stream)
{
    const float* feat   = (const float*)d_in[0];
    const float* W      = (const float*)d_in[1];
    const float* av     = (const float*)d_in[2];
    const int*   adj1   = (const int*)d_in[3];
    const int*   adj2   = (const int*)d_in[4];
    const int*   labels = (const int*)d_in[5];
    const int*   idxt   = (const int*)d_in[6];

    const size_t HEAD = (1u << 20) + (192u << 10);  // Vt2 1MB + sQ 128KB + dE1/2 64KB

    auto needed = [&](int scl) -> size_t {
        const size_t SC = (size_t)1 << scl;
        return HEAD + 2 * SC * NTRAIN * CDIM * sizeof(unsigned short)  // numPartB
                    + 2 * SC * NTRAIN * sizeof(float)                  // zPart
                    + NTRAIN * sizeof(float);
    };
    const int scLog2 = (ws_size >= needed(5)) ? 5 : 4;
    const int SC = 1 << scLog2;

    char* ws = (char*)d_ws;
    unsigned short* Vt2 = (unsigned short*)ws;                  // 1 MB
    float4* sQ  = (float4*)(ws + (1u << 20));                   // 128 KB
    float*  dE1 = (float*)(ws + (1u << 20) + (128u << 10));     // 32 KB
    float*  dE2 = (float*)(ws + (1u << 20) + (160u << 10));     // 32 KB
    unsigned short* numPartB = (unsigned short*)(ws + HEAD);
    float*  zPart  = (float*)((char*)numPartB
                              + 2ull * SC * NTRAIN * CDIM * sizeof(unsigned short));
    float*  losses = zPart + 2ull * SC * NTRAIN;

    hipLaunchKernelGGL(k_wh, dim3(512), dim3(256), 0, stream,
                       feat, W, av, Vt2, sQ, dE1, dE2);
    if (scLog2 == 5)
        hipLaunchKernelGGL((k_mattn<5>), dim3(32 * 32), dim3(256), 0, stream,
                           adj1, adj2, Vt2, sQ, dE1, dE2, idxt, numPartB, zPart);
    else
        hipLaunchKernelGGL((k_mattn<4>), dim3(32 * 16), dim3(256), 0, stream,
                           adj1, adj2, Vt2, sQ, dE1, dE2, idxt, numPartB, zPart);
    hipLaunchKernelGGL(k_loss, dim3(NTRAIN / 4), dim3(256), 0, stream,
                       numPartB, zPart, labels, idxt, losses, scLog2);
    hipLaunchKernelGGL(k_reduce, dim3(1), dim3(256), 0, stream,
                       losses, (float*)d_out);
}